// Round 1
// baseline (828.079 us; speedup 1.0000x reference)
//
#include <hip/hip_runtime.h>
#include <math.h>

// Problem constants (match reference setup_inputs)
#define B_ 8
#define H_ 512
#define E_ 256
#define T_ 2048
#define S_ 2048
static constexpr float SCALE = 0.83666002653407555f; // sqrt(0.7)

// GEMM tile config: 64x64 block tile, K-tile 16, 256 threads, 4x4 micro-tile
#define BM 64
#define BN 64
#define BK 16

__device__ __forceinline__ void micro_fma(const float As[BK][BM + 4],
                                          const float Bs[BK][BN + 4],
                                          float acc[4][4], int tm, int tn) {
#pragma unroll
    for (int k = 0; k < BK; ++k) {
        const float4 a4 = *(const float4*)(&As[k][tm * 4]);
        const float4 b4 = *(const float4*)(&Bs[k][tn * 4]);
        acc[0][0] += a4.x * b4.x; acc[0][1] += a4.x * b4.y; acc[0][2] += a4.x * b4.z; acc[0][3] += a4.x * b4.w;
        acc[1][0] += a4.y * b4.x; acc[1][1] += a4.y * b4.y; acc[1][2] += a4.y * b4.z; acc[1][3] += a4.y * b4.w;
        acc[2][0] += a4.z * b4.x; acc[2][1] += a4.z * b4.y; acc[2][2] += a4.z * b4.z; acc[2][3] += a4.z * b4.w;
        acc[3][0] += a4.w * b4.x; acc[3][1] += a4.w * b4.y; acc[3][2] += a4.w * b4.z; acc[3][3] += a4.w * b4.w;
    }
}

// K1: Q[b,t,e] = (sum_h dec[b,h,t] * W_h2e[e,h] + b_h2e[e] + emb[b,t,e]) * SCALE
__global__ __launch_bounds__(256) void k_q(const float* __restrict__ dec,
                                           const float* __restrict__ emb,
                                           const float* __restrict__ W,
                                           const float* __restrict__ bias,
                                           float* __restrict__ Q) {
    __shared__ __align__(16) float As[BK][BM + 4];
    __shared__ __align__(16) float Bs[BK][BN + 4];
    const int b = blockIdx.z;
    const int t0 = blockIdx.y * BM;
    const int e0 = blockIdx.x * BN;
    const int tid = threadIdx.x;
    const int tm = tid >> 4, tn = tid & 15;
    const int ak = tid >> 4;          // A-style: 16 rows x 64 cols (float4)
    const int am = (tid & 15) * 4;
    const int bn = tid >> 2;          // B-style: 64 rows x 16 (float4 along k)
    const int bk = (tid & 3) * 4;
    float acc[4][4] = {};
    const float* decb = dec + (size_t)b * H_ * T_;

    for (int h0 = 0; h0 < H_; h0 += BK) {
        // As[k][m] = dec[b, h0+k, t0+m]  (contiguous in t -> float4)
        const float4 av = *(const float4*)(decb + (size_t)(h0 + ak) * T_ + t0 + am);
        *(float4*)(&As[ak][am]) = av;
        // Bs[k][n] = W[(e0+n)*H + h0+k]  (contiguous in k -> float4)
        const float4 bv = *(const float4*)(W + (size_t)(e0 + bn) * H_ + h0 + bk);
        Bs[bk + 0][bn] = bv.x; Bs[bk + 1][bn] = bv.y; Bs[bk + 2][bn] = bv.z; Bs[bk + 3][bn] = bv.w;
        __syncthreads();
        micro_fma(As, Bs, acc, tm, tn);
        __syncthreads();
    }

    const float4 b4 = *(const float4*)(bias + e0 + tn * 4);
    const float* embb = emb + (size_t)b * T_ * E_;
    float* Qb = Q + (size_t)b * T_ * E_;
#pragma unroll
    for (int i = 0; i < 4; ++i) {
        const int t = t0 + tm * 4 + i;
        const float4 e4 = *(const float4*)(embb + (size_t)t * E_ + e0 + tn * 4);
        float4 o;
        o.x = (acc[i][0] + b4.x + e4.x) * SCALE;
        o.y = (acc[i][1] + b4.y + e4.y) * SCALE;
        o.z = (acc[i][2] + b4.z + e4.z) * SCALE;
        o.w = (acc[i][3] + b4.w + e4.w) * SCALE;
        *(float4*)(Qb + (size_t)t * E_ + e0 + tn * 4) = o;
    }
}

// K2: energy[b,t,s] = sum_e Q[b,t,e] * en_conved[b,s,e]   (written to a-region)
__global__ __launch_bounds__(256) void k_energy(const float* __restrict__ Q,
                                                const float* __restrict__ Kc,
                                                float* __restrict__ a_out) {
    __shared__ __align__(16) float As[BK][BM + 4];
    __shared__ __align__(16) float Bs[BK][BN + 4];
    const int b = blockIdx.z;
    const int t0 = blockIdx.y * BM;
    const int s0 = blockIdx.x * BN;
    const int tid = threadIdx.x;
    const int tm = tid >> 4, tn = tid & 15;
    const int bn = tid >> 2;
    const int bk = (tid & 3) * 4;
    float acc[4][4] = {};
    const float* Qb = Q + (size_t)b * T_ * E_;
    const float* Kb = Kc + (size_t)b * S_ * E_;

    for (int e0 = 0; e0 < E_; e0 += BK) {
        const float4 av = *(const float4*)(Qb + (size_t)(t0 + bn) * E_ + e0 + bk);
        As[bk + 0][bn] = av.x; As[bk + 1][bn] = av.y; As[bk + 2][bn] = av.z; As[bk + 3][bn] = av.w;
        const float4 bv = *(const float4*)(Kb + (size_t)(s0 + bn) * E_ + e0 + bk);
        Bs[bk + 0][bn] = bv.x; Bs[bk + 1][bn] = bv.y; Bs[bk + 2][bn] = bv.z; Bs[bk + 3][bn] = bv.w;
        __syncthreads();
        micro_fma(As, Bs, acc, tm, tn);
        __syncthreads();
    }

    float* ab = a_out + (size_t)b * T_ * S_;
#pragma unroll
    for (int i = 0; i < 4; ++i) {
        const int t = t0 + tm * 4 + i;
        float4 o; o.x = acc[i][0]; o.y = acc[i][1]; o.z = acc[i][2]; o.w = acc[i][3];
        *(float4*)(ab + (size_t)t * S_ + s0 + tn * 4) = o;
    }
}

// K3: in-place softmax over last dim (S=2048), one block per row
__global__ __launch_bounds__(256) void k_softmax(float* __restrict__ a) {
    const size_t row = blockIdx.x;
    float* p = a + row * (size_t)S_;
    float4 v0 = ((const float4*)p)[threadIdx.x];
    float4 v1 = ((const float4*)p)[threadIdx.x + 256];

    float m = fmaxf(fmaxf(fmaxf(v0.x, v0.y), fmaxf(v0.z, v0.w)),
                    fmaxf(fmaxf(v1.x, v1.y), fmaxf(v1.z, v1.w)));
#pragma unroll
    for (int off = 32; off > 0; off >>= 1) m = fmaxf(m, __shfl_down(m, off));
    __shared__ float redm[4];
    __shared__ float reds[4];
    const int wid = threadIdx.x >> 6, lane = threadIdx.x & 63;
    if (lane == 0) redm[wid] = m;
    __syncthreads();
    m = fmaxf(fmaxf(redm[0], redm[1]), fmaxf(redm[2], redm[3]));

    v0.x = __expf(v0.x - m); v0.y = __expf(v0.y - m); v0.z = __expf(v0.z - m); v0.w = __expf(v0.w - m);
    v1.x = __expf(v1.x - m); v1.y = __expf(v1.y - m); v1.z = __expf(v1.z - m); v1.w = __expf(v1.w - m);
    float s = v0.x + v0.y + v0.z + v0.w + v1.x + v1.y + v1.z + v1.w;
#pragma unroll
    for (int off = 32; off > 0; off >>= 1) s += __shfl_down(s, off);
    if (lane == 0) reds[wid] = s;
    __syncthreads();
    s = reds[0] + reds[1] + reds[2] + reds[3];
    const float inv = 1.0f / s;

    v0.x *= inv; v0.y *= inv; v0.z *= inv; v0.w *= inv;
    v1.x *= inv; v1.y *= inv; v1.z *= inv; v1.w *= inv;
    ((float4*)p)[threadIdx.x] = v0;
    ((float4*)p)[threadIdx.x + 256] = v1;
}

// K4: context[b,t,e] = sum_s a[b,t,s] * en_combined[b,s,e]
__global__ __launch_bounds__(256) void k_ctx(const float* __restrict__ a,
                                             const float* __restrict__ V,
                                             float* __restrict__ ctx) {
    __shared__ __align__(16) float As[BK][BM + 4];
    __shared__ __align__(16) float Bs[BK][BN + 4];
    const int b = blockIdx.z;
    const int t0 = blockIdx.y * BM;
    const int e0 = blockIdx.x * BN;
    const int tid = threadIdx.x;
    const int tm = tid >> 4, tn = tid & 15;
    const int ak = tid >> 4;
    const int am = (tid & 15) * 4;
    const int bn = tid >> 2;
    const int bk = (tid & 3) * 4;
    float acc[4][4] = {};
    const float* ab = a + (size_t)b * T_ * S_;
    const float* Vb = V + (size_t)b * S_ * E_;

    for (int s0 = 0; s0 < S_; s0 += BK) {
        const float4 av = *(const float4*)(ab + (size_t)(t0 + bn) * S_ + s0 + bk);
        As[bk + 0][bn] = av.x; As[bk + 1][bn] = av.y; As[bk + 2][bn] = av.z; As[bk + 3][bn] = av.w;
        const float4 bv = *(const float4*)(Vb + (size_t)(s0 + ak) * E_ + e0 + am);
        *(float4*)(&Bs[ak][am]) = bv;
        __syncthreads();
        micro_fma(As, Bs, acc, tm, tn);
        __syncthreads();
    }

    float* cb = ctx + (size_t)b * T_ * E_;
#pragma unroll
    for (int i = 0; i < 4; ++i) {
        const int t = t0 + tm * 4 + i;
        float4 o; o.x = acc[i][0]; o.y = acc[i][1]; o.z = acc[i][2]; o.w = acc[i][3];
        *(float4*)(cb + (size_t)t * E_ + e0 + tn * 4) = o;
    }
}

// K5: out[b,h,t] = (sum_e ctx[b,t,e]*W_e2h[h,e] + b_e2h[h] + dec[b,h,t]) * SCALE
__global__ __launch_bounds__(256) void k_out(const float* __restrict__ ctx,
                                             const float* __restrict__ W,
                                             const float* __restrict__ bias,
                                             const float* __restrict__ dec,
                                             float* __restrict__ out) {
    __shared__ __align__(16) float As[BK][BM + 4];
    __shared__ __align__(16) float Bs[BK][BN + 4];
    const int b = blockIdx.z;
    const int t0 = blockIdx.y * BM;   // M = t
    const int h0 = blockIdx.x * BN;   // N = h
    const int tid = threadIdx.x;
    const int tm = tid >> 4, tn = tid & 15;
    const int bn = tid >> 2;
    const int bk = (tid & 3) * 4;
    float acc[4][4] = {};
    const float* cb = ctx + (size_t)b * T_ * E_;

    for (int e0 = 0; e0 < E_; e0 += BK) {
        const float4 av = *(const float4*)(cb + (size_t)(t0 + bn) * E_ + e0 + bk);
        As[bk + 0][bn] = av.x; As[bk + 1][bn] = av.y; As[bk + 2][bn] = av.z; As[bk + 3][bn] = av.w;
        const float4 bv = *(const float4*)(W + (size_t)(h0 + bn) * E_ + e0 + bk);
        Bs[bk + 0][bn] = bv.x; Bs[bk + 1][bn] = bv.y; Bs[bk + 2][bn] = bv.z; Bs[bk + 3][bn] = bv.w;
        __syncthreads();
        micro_fma(As, Bs, acc, tm, tn);
        __syncthreads();
    }

    const float* decb = dec + (size_t)b * H_ * T_;
    float* ob = out + (size_t)b * H_ * T_;
#pragma unroll
    for (int j = 0; j < 4; ++j) {
        const int h = h0 + tn * 4 + j;
        const float bj = bias[h];
#pragma unroll
        for (int i = 0; i < 4; ++i) {
            const int t = t0 + tm * 4 + i;
            const size_t idx = (size_t)h * T_ + t;
            ob[idx] = (acc[i][j] + bj + decb[idx]) * SCALE;
        }
    }
}

extern "C" void kernel_launch(void* const* d_in, const int* in_sizes, int n_in,
                              void* d_out, int out_size, void* d_ws, size_t ws_size,
                              hipStream_t stream) {
    const float* dec    = (const float*)d_in[0];  // [B,H,T]
    const float* emb    = (const float*)d_in[1];  // [B,T,E]
    const float* enc    = (const float*)d_in[2];  // [B,S,E] en_conved
    const float* encc   = (const float*)d_in[3];  // [B,S,E] en_combined
    const float* W_h2e  = (const float*)d_in[4];  // [E,H]
    const float* b_h2e  = (const float*)d_in[5];  // [E]
    const float* W_e2h  = (const float*)d_in[6];  // [H,E]
    const float* b_e2h  = (const float*)d_in[7];  // [H]

    float* a_out = (float*)d_out;                       // [B,T,S]
    float* out2  = a_out + (size_t)B_ * T_ * S_;        // [B,H,T]
    float* Q     = (float*)d_ws;                        // [B,T,E]
    float* CTX   = Q + (size_t)B_ * T_ * E_;            // [B,T,E]

    const dim3 blk(256);
    k_q      <<<dim3(E_ / BN, T_ / BM, B_), blk, 0, stream>>>(dec, emb, W_h2e, b_h2e, Q);
    k_energy <<<dim3(S_ / BN, T_ / BM, B_), blk, 0, stream>>>(Q, enc, a_out);
    k_softmax<<<dim3(B_ * T_),              blk, 0, stream>>>(a_out);
    k_ctx    <<<dim3(E_ / BN, T_ / BM, B_), blk, 0, stream>>>(a_out, encc, CTX);
    k_out    <<<dim3(H_ / BN, T_ / BM, B_), blk, 0, stream>>>(CTX, W_e2h, b_e2h, dec, out2);
}

// Round 3
// 407.065 us; speedup vs baseline: 2.0343x; 2.0343x over previous
//
#include <hip/hip_runtime.h>
#include <math.h>

#define B_ 8
#define H_ 512
#define E_ 256
#define T_ 2048
#define S_ 2048
static constexpr float SCALE = 0.83666002653407555f; // sqrt(0.7)

typedef _Float16 half8 __attribute__((ext_vector_type(8)));
typedef _Float16 half4v __attribute__((ext_vector_type(4)));
typedef float f32x4 __attribute__((ext_vector_type(4)));

// ---- elementwise fp32 -> fp16 cast (8 elems / thread) ----
__global__ __launch_bounds__(256) void k_cast(const float* __restrict__ in,
                                              _Float16* __restrict__ out, int n8) {
    const int i = blockIdx.x * 256 + threadIdx.x;
    if (i >= n8) return;
    const float4* p = (const float4*)(in + (size_t)i * 8);
    const float4 a = p[0], b = p[1];
    half8 v;
    v[0] = (_Float16)a.x; v[1] = (_Float16)a.y; v[2] = (_Float16)a.z; v[3] = (_Float16)a.w;
    v[4] = (_Float16)b.x; v[5] = (_Float16)b.y; v[6] = (_Float16)b.z; v[7] = (_Float16)b.w;
    *(half8*)(out + (size_t)i * 8) = v;
}

// ---- transpose + cast: in fp32 [Z, R, C] -> out fp16 [Z, C, R] ----
__global__ __launch_bounds__(256) void k_tcast(const float* __restrict__ in,
                                               _Float16* __restrict__ out, int R, int C) {
    __shared__ float tile[32][33];
    const size_t nb = (size_t)R * C;
    const float* inb = in + (size_t)blockIdx.z * nb;
    _Float16* outb = out + (size_t)blockIdx.z * nb;
    const int c0 = blockIdx.x * 32, r0 = blockIdx.y * 32;
    const int tr = threadIdx.x >> 3;
    const int tc = (threadIdx.x & 7) * 4;
    const float4 v = *(const float4*)(inb + (size_t)(r0 + tr) * C + c0 + tc);
    tile[tr][tc + 0] = v.x; tile[tr][tc + 1] = v.y;
    tile[tr][tc + 2] = v.z; tile[tr][tc + 3] = v.w;
    __syncthreads();
    half4v o;
    o[0] = (_Float16)tile[tc + 0][tr]; o[1] = (_Float16)tile[tc + 1][tr];
    o[2] = (_Float16)tile[tc + 2][tr]; o[3] = (_Float16)tile[tc + 3][tr];
    *(half4v*)(outb + (size_t)(c0 + tr) * R + r0 + tc) = o;
}

// ---- stage a 128x32 fp16 tile (rows k-contiguous, ld elements) into LDS ----
__device__ __forceinline__ void stage128x32(const _Float16* __restrict__ g, int ld,
                                            _Float16* __restrict__ lds, int tid) {
    const int r = tid >> 2;
    const int c = (tid & 3) * 8;
    const half8 v0 = *(const half8*)(g + (size_t)r * ld + c);
    const half8 v1 = *(const half8*)(g + (size_t)(r + 64) * ld + c);
    *(half8*)(lds + r * 32 + c) = v0;
    *(half8*)(lds + (r + 64) * 32 + c) = v1;
}

// ---- stage a 128x32 fp32 tile, converting to fp16 in LDS ----
__device__ __forceinline__ void stage_f32_128x32(const float* __restrict__ g, int ld,
                                                 _Float16* __restrict__ lds, int tid) {
    const int r = tid >> 1;
    const int c = (tid & 1) * 16;
    const float4* gp = (const float4*)(g + (size_t)r * ld + c);
    const float4 x0 = gp[0], x1 = gp[1], x2 = gp[2], x3 = gp[3];
    half8 v0, v1;
    v0[0] = (_Float16)x0.x; v0[1] = (_Float16)x0.y; v0[2] = (_Float16)x0.z; v0[3] = (_Float16)x0.w;
    v0[4] = (_Float16)x1.x; v0[5] = (_Float16)x1.y; v0[6] = (_Float16)x1.z; v0[7] = (_Float16)x1.w;
    v1[0] = (_Float16)x2.x; v1[1] = (_Float16)x2.y; v1[2] = (_Float16)x2.z; v1[3] = (_Float16)x2.w;
    v1[4] = (_Float16)x3.x; v1[5] = (_Float16)x3.y; v1[6] = (_Float16)x3.z; v1[7] = (_Float16)x3.w;
    *(half8*)(lds + r * 32 + c) = v0;
    *(half8*)(lds + r * 32 + c + 8) = v1;
}

#define MFMA_PROLOG                                                     \
    __shared__ __align__(16) _Float16 Ash[128 * 32];                    \
    __shared__ __align__(16) _Float16 Bsh[128 * 32];                    \
    const int tid = threadIdx.x;                                        \
    const int lane = tid & 63, wv = tid >> 6;                           \
    const int wm = (wv >> 1) * 64, wn = (wv & 1) * 64;                  \
    const int fr = lane & 15, fk = (lane >> 4) * 8;                     \
    f32x4 acc[4][4] = {};

#define MFMA_BODY                                                       \
    half8 af[4], bfr[4];                                                \
    _Pragma("unroll")                                                   \
    for (int i = 0; i < 4; ++i) {                                       \
        af[i]  = *(const half8*)&Ash[(wm + i * 16 + fr) * 32 + fk];     \
        bfr[i] = *(const half8*)&Bsh[(wn + i * 16 + fr) * 32 + fk];     \
    }                                                                   \
    _Pragma("unroll")                                                   \
    for (int mi = 0; mi < 4; ++mi)                                      \
        _Pragma("unroll")                                               \
        for (int ni = 0; ni < 4; ++ni)                                  \
            acc[mi][ni] = __builtin_amdgcn_mfma_f32_16x16x32_f16(       \
                af[mi], bfr[ni], acc[mi][ni], 0, 0, 0);

// K1: Q_f16[b,t,e] = f16((decT.W1^T + b_h2e + emb) * SCALE)
// A=decT [T,H] ld H, B=W1 [E,H] ld H, K=H
__global__ __launch_bounds__(256) void k_q_mfma(const _Float16* __restrict__ decT,
                                                const _Float16* __restrict__ W1,
                                                const float* __restrict__ bias,
                                                const float* __restrict__ emb,
                                                _Float16* __restrict__ Qb) {
    MFMA_PROLOG
    const int b = blockIdx.z;
    const int t0 = blockIdx.y * 128;
    const int e0 = blockIdx.x * 128;
    const _Float16* Ab = decT + (size_t)b * T_ * H_ + (size_t)t0 * H_;
    const _Float16* Bb = W1 + (size_t)e0 * H_;
    for (int k0 = 0; k0 < H_; k0 += 32) {
        stage128x32(Ab + k0, H_, Ash, tid);
        stage128x32(Bb + k0, H_, Bsh, tid);
        __syncthreads();
        MFMA_BODY
        __syncthreads();
    }
    const int cr = (lane >> 4) * 4, cn = lane & 15;
    const float* embb = emb + (size_t)b * T_ * E_;
    _Float16* Qo = Qb + (size_t)b * T_ * E_;
#pragma unroll
    for (int mi = 0; mi < 4; ++mi)
#pragma unroll
        for (int r = 0; r < 4; ++r) {
            const int t = t0 + wm + mi * 16 + cr + r;
#pragma unroll
            for (int ni = 0; ni < 4; ++ni) {
                const int e = e0 + wn + ni * 16 + cn;
                const float v = (acc[mi][ni][r] + bias[e] + embb[(size_t)t * E_ + e]) * SCALE;
                Qo[(size_t)t * E_ + e] = (_Float16)v;
            }
        }
}

// K2: energy[b,t,s] = Q . enc   A=Q_f16 [T,E], B=enc_f16 [S,E], K=E
__global__ __launch_bounds__(256) void k_energy_mfma(const _Float16* __restrict__ Qb,
                                                     const _Float16* __restrict__ Kb,
                                                     float* __restrict__ a_out) {
    MFMA_PROLOG
    const int b = blockIdx.z;
    const int t0 = blockIdx.y * 128;
    const int s0 = blockIdx.x * 128;
    const _Float16* Ab = Qb + (size_t)b * T_ * E_ + (size_t)t0 * E_;
    const _Float16* Bb = Kb + (size_t)b * S_ * E_ + (size_t)s0 * E_;
    for (int k0 = 0; k0 < E_; k0 += 32) {
        stage128x32(Ab + k0, E_, Ash, tid);
        stage128x32(Bb + k0, E_, Bsh, tid);
        __syncthreads();
        MFMA_BODY
        __syncthreads();
    }
    const int cr = (lane >> 4) * 4, cn = lane & 15;
    float* ab = a_out + (size_t)b * T_ * S_;
#pragma unroll
    for (int mi = 0; mi < 4; ++mi)
#pragma unroll
        for (int r = 0; r < 4; ++r) {
            const int t = t0 + wm + mi * 16 + cr + r;
#pragma unroll
            for (int ni = 0; ni < 4; ++ni) {
                const int s = s0 + wn + ni * 16 + cn;
                ab[(size_t)t * S_ + s] = acc[mi][ni][r];
            }
        }
}

// K3: in-place softmax over last dim (S=2048), one block per row
__global__ __launch_bounds__(256) void k_softmax(float* __restrict__ a) {
    const size_t row = blockIdx.x;
    float* p = a + row * (size_t)S_;
    float4 v0 = ((const float4*)p)[threadIdx.x];
    float4 v1 = ((const float4*)p)[threadIdx.x + 256];

    float m = fmaxf(fmaxf(fmaxf(v0.x, v0.y), fmaxf(v0.z, v0.w)),
                    fmaxf(fmaxf(v1.x, v1.y), fmaxf(v1.z, v1.w)));
#pragma unroll
    for (int off = 32; off > 0; off >>= 1) m = fmaxf(m, __shfl_down(m, off));
    __shared__ float redm[4];
    __shared__ float reds[4];
    const int wid = threadIdx.x >> 6, lane = threadIdx.x & 63;
    if (lane == 0) redm[wid] = m;
    __syncthreads();
    m = fmaxf(fmaxf(redm[0], redm[1]), fmaxf(redm[2], redm[3]));

    v0.x = __expf(v0.x - m); v0.y = __expf(v0.y - m); v0.z = __expf(v0.z - m); v0.w = __expf(v0.w - m);
    v1.x = __expf(v1.x - m); v1.y = __expf(v1.y - m); v1.z = __expf(v1.z - m); v1.w = __expf(v1.w - m);
    float s = v0.x + v0.y + v0.z + v0.w + v1.x + v1.y + v1.z + v1.w;
#pragma unroll
    for (int off = 32; off > 0; off >>= 1) s += __shfl_down(s, off);
    if (lane == 0) reds[wid] = s;
    __syncthreads();
    s = reds[0] + reds[1] + reds[2] + reds[3];
    const float inv = 1.0f / s;

    v0.x *= inv; v0.y *= inv; v0.z *= inv; v0.w *= inv;
    v1.x *= inv; v1.y *= inv; v1.z *= inv; v1.w *= inv;
    ((float4*)p)[threadIdx.x] = v0;
    ((float4*)p)[threadIdx.x + 256] = v1;
}

// K4: ctx_f16[b,t,e] = a . en_combined   A=a fp32 [T,S] (cvt at staging),
// B=enccT_f16 [E,S] ld S, K=S
__global__ __launch_bounds__(256) void k_ctx_mfma(const float* __restrict__ a,
                                                  const _Float16* __restrict__ Vt,
                                                  _Float16* __restrict__ ctxb) {
    MFMA_PROLOG
    const int b = blockIdx.z;
    const int t0 = blockIdx.y * 128;
    const int e0 = blockIdx.x * 128;
    const float* Ab = a + (size_t)b * T_ * S_ + (size_t)t0 * S_;
    const _Float16* Bb = Vt + (size_t)b * E_ * S_ + (size_t)e0 * S_;
    for (int k0 = 0; k0 < S_; k0 += 32) {
        stage_f32_128x32(Ab + k0, S_, Ash, tid);
        stage128x32(Bb + k0, S_, Bsh, tid);
        __syncthreads();
        MFMA_BODY
        __syncthreads();
    }
    const int cr = (lane >> 4) * 4, cn = lane & 15;
    _Float16* co = ctxb + (size_t)b * T_ * E_;
#pragma unroll
    for (int mi = 0; mi < 4; ++mi)
#pragma unroll
        for (int r = 0; r < 4; ++r) {
            const int t = t0 + wm + mi * 16 + cr + r;
#pragma unroll
            for (int ni = 0; ni < 4; ++ni) {
                const int e = e0 + wn + ni * 16 + cn;
                co[(size_t)t * E_ + e] = (_Float16)acc[mi][ni][r];
            }
        }
}

// K5: out[b,h,t] = (W2 . ctx^T + b_e2h + dec) * SCALE
// Transposed problem: M=h (A=W2 [H,E]), N=t (B=ctx_f16 [T,E]), K=E -> coalesced [B,H,T] store
__global__ __launch_bounds__(256) void k_out_mfma(const _Float16* __restrict__ W2,
                                                  const _Float16* __restrict__ ctxb,
                                                  const float* __restrict__ bias,
                                                  const float* __restrict__ dec,
                                                  float* __restrict__ out2) {
    MFMA_PROLOG
    const int b = blockIdx.z;
    const int h0 = blockIdx.y * 128;
    const int t0 = blockIdx.x * 128;
    const _Float16* Ab = W2 + (size_t)h0 * E_;
    const _Float16* Bb = ctxb + (size_t)b * T_ * E_ + (size_t)t0 * E_;
    for (int k0 = 0; k0 < E_; k0 += 32) {
        stage128x32(Ab + k0, E_, Ash, tid);
        stage128x32(Bb + k0, E_, Bsh, tid);
        __syncthreads();
        MFMA_BODY
        __syncthreads();
    }
    const int cr = (lane >> 4) * 4, cn = lane & 15;
    const float* decb = dec + (size_t)b * H_ * T_;
    float* ob = out2 + (size_t)b * H_ * T_;
#pragma unroll
    for (int mi = 0; mi < 4; ++mi)
#pragma unroll
        for (int r = 0; r < 4; ++r) {
            const int h = h0 + wm + mi * 16 + cr + r;
            const float bj = bias[h];
#pragma unroll
            for (int ni = 0; ni < 4; ++ni) {
                const int t = t0 + wn + ni * 16 + cn;
                const size_t idx = (size_t)h * T_ + t;
                ob[idx] = (acc[mi][ni][r] + bj + decb[idx]) * SCALE;
            }
        }
}

extern "C" void kernel_launch(void* const* d_in, const int* in_sizes, int n_in,
                              void* d_out, int out_size, void* d_ws, size_t ws_size,
                              hipStream_t stream) {
    const float* dec   = (const float*)d_in[0];  // [B,H,T]
    const float* emb   = (const float*)d_in[1];  // [B,T,E]
    const float* enc   = (const float*)d_in[2];  // [B,S,E] en_conved
    const float* encc  = (const float*)d_in[3];  // [B,S,E] en_combined
    const float* W_h2e = (const float*)d_in[4];  // [E,H]
    const float* b_h2e = (const float*)d_in[5];  // [E]
    const float* W_e2h = (const float*)d_in[6];  // [H,E]
    const float* b_e2h = (const float*)d_in[7];  // [H]

    float* a_out = (float*)d_out;                 // [B,T,S]
    float* out2  = a_out + (size_t)B_ * T_ * S_;  // [B,H,T]

    _Float16* ws    = (_Float16*)d_ws;
    _Float16* decT  = ws;                                  // [B,T,H] f16
    _Float16* encK  = decT + (size_t)B_ * T_ * H_;         // [B,S,E] f16
    _Float16* enccT = encK + (size_t)B_ * S_ * E_;         // [B,E,S] f16
    _Float16* W1b   = enccT + (size_t)B_ * S_ * E_;        // [E,H] f16
    _Float16* W2b   = W1b + (size_t)E_ * H_;               // [H,E] f16
    _Float16* Qb    = W2b + (size_t)H_ * E_;               // [B,T,E] f16
    _Float16* ctxb  = Qb + (size_t)B_ * T_ * E_;           // [B,T,E] f16

    const dim3 blk(256);
    // casts
    k_cast <<<dim3((B_ * S_ * E_ / 8 + 255) / 256), blk, 0, stream>>>(enc, encK, B_ * S_ * E_ / 8);
    k_cast <<<dim3((E_ * H_ / 8 + 255) / 256),      blk, 0, stream>>>(W_h2e, W1b, E_ * H_ / 8);
    k_cast <<<dim3((H_ * E_ / 8 + 255) / 256),      blk, 0, stream>>>(W_e2h, W2b, H_ * E_ / 8);
    k_tcast<<<dim3(T_ / 32, H_ / 32, B_), blk, 0, stream>>>(dec, decT, H_, T_);   // [H,T]->[T,H]
    k_tcast<<<dim3(E_ / 32, S_ / 32, B_), blk, 0, stream>>>(encc, enccT, S_, E_); // [S,E]->[E,S]
    // pipeline
    k_q_mfma     <<<dim3(E_ / 128, T_ / 128, B_), blk, 0, stream>>>(decT, W1b, b_h2e, emb, Qb);
    k_energy_mfma<<<dim3(S_ / 128, T_ / 128, B_), blk, 0, stream>>>(Qb, encK, a_out);
    k_softmax    <<<dim3(B_ * T_),                blk, 0, stream>>>(a_out);
    k_ctx_mfma   <<<dim3(E_ / 128, T_ / 128, B_), blk, 0, stream>>>(a_out, enccT, ctxb);
    k_out_mfma   <<<dim3(T_ / 128, H_ / 128, B_), blk, 0, stream>>>(W2b, ctxb, b_e2h, dec, out2);
}